// Round 5
// baseline (82.639 us; speedup 1.0000x reference)
//
#include <hip/hip_runtime.h>
#include <float.h>

#define BB 16
#define MM 32
#define KK 20
#define AA 8
#define TT 30
#define TD 60          // T*D floats per trajectory
#define NS 15          // float4 steps per trajectory (2 t-steps each)
#define KT 22          // target rows: 20 real + gt (row 20) + dummy (row 21)
#define PDS 21         // pd row stride in floats

typedef float v2f __attribute__((ext_vector_type(2)));

// One block = 4 waves = 2 m's x 2 tile-halves, for a fixed (b, a).
// grid = B*A*(M/2) = 2048 blocks of 256 -> 8 blocks/CU (LDS 18.25 KB)
// -> 32 waves/CU (8/SIMD) = max occupancy. R2 counters showed the compute
// structure is latency-bound (VALUBusy 11%, HBM 2%) at 16 waves/CU; the
// i-split halves per-wave work with IDENTICAL per-cell FP order (each pd
// cell still summed by one lane over s=0..14), so absmax stays 0.
// Wave w: m = w&1, half = w>>1, rows k = tk + 10*half + {0,5}.
__global__ __launch_bounds__(256, 8) void imle_part_kernel(
    const float* __restrict__ gen,   // B M K A T D
    const float* __restrict__ tgt,   // B K A T D
    const float* __restrict__ gt,    // B A T D
    float* __restrict__ ws_cham,     // [B][M][A]
    float* __restrict__ ws_gt)       // [B][M][A]
{
    __shared__ float4 sg[2][KK][NS];   // 2 m-slices of gen, x50, swizzled
    __shared__ float4 st[KT][NS];      // target rows (x50) + gt row + dummy
    __shared__ float  pd[2][KK][PDS];  // per-m pairwise mean distances

    const int blk = blockIdx.x;        // grid = 2048
    const int mg = blk & 15;           // m-group (M/2 = 16)
    const int a  = (blk >> 4) & 7;
    const int b  = blk >> 7;
    const int m0 = mg * 2;
    const int tid = threadIdx.x;

    // ---- merged staging: 600 gen float4 + 330 target float4, 256 threads ----
    // swizzle (x1,y1,x2,y2) -> (x1,x2,y1,y2) for packed v2f math
    for (int idx = tid; idx < (40 + KT) * NS; idx += 256) {
        int row = idx / NS, q = idx - row * NS;
        if (row < 40) {                       // gen rows
            int mi = row / KK, k = row - mi * KK;
            float4 v = ((const float4*)(gen +
                (size_t)(((b * MM + m0 + mi) * KK + k) * AA + a) * TD))[q];
            sg[mi][k][q] = make_float4(v.x * 50.f, v.z * 50.f, v.y * 50.f, v.w * 50.f);
        } else {
            int r = row - 40;                 // target rows
            float4 v;
            if (r < KK) {
                v = ((const float4*)(tgt + (size_t)((b * KK + r) * AA + a) * TD))[q];
                v = make_float4(v.x * 50.f, v.z * 50.f, v.y * 50.f, v.w * 50.f);
            } else if (r == KK) {
                v = ((const float4*)(gt + (size_t)(b * AA + a) * TD))[q];
                v = make_float4(v.x, v.z, v.y, v.w);
            } else {
                v = make_float4(0.f, 0.f, 0.f, 0.f);
            }
            st[r][q] = v;
        }
    }
    __syncthreads();

    const int w = tid >> 6;        // wave id
    const int m = w & 1;           // which m of the pair
    const int half = w >> 1;       // which half of the 4-row register tile
    const int lane = tid & 63;

    // ---- pairwise distances: 2x2 register tile per wave, pipelined s-loop ----
    if (lane < 55) {
        const int tk  = lane / 11;             // k = kb + 5*ii
        const int tkp = lane - tk * 11;        // kp = tkp + 11j
        const int kb  = tk + 10 * half;        // row base for this wave
        v2f acc[2][2] = {{{0.f,0.f},{0.f,0.f}},{{0.f,0.f},{0.f,0.f}}};

        float4 gv[2], tv[2];
#pragma unroll
        for (int i = 0; i < 2; ++i) gv[i] = sg[m][kb + 5 * i][0];
        tv[0] = st[tkp][0];
        tv[1] = st[tkp + 11][0];

#pragma unroll 2
        for (int s = 0; s < NS - 1; ++s) {
            // prefetch s+1 (independent of current compute)
            float4 ngv[2], ntv[2];
#pragma unroll
            for (int i = 0; i < 2; ++i) ngv[i] = sg[m][kb + 5 * i][s + 1];
            ntv[0] = st[tkp][s + 1];
            ntv[1] = st[tkp + 11][s + 1];
            // compute on current: packed over the 2 t-steps in each float4
#pragma unroll
            for (int i = 0; i < 2; ++i) {
                v2f gx = {gv[i].x, gv[i].y};   // (x_t, x_{t+1})
                v2f gy = {gv[i].z, gv[i].w};   // (y_t, y_{t+1})
#pragma unroll
                for (int j = 0; j < 2; ++j) {
                    v2f dx = gx - (v2f){tv[j].x, tv[j].y};
                    v2f dy = gy - (v2f){tv[j].z, tv[j].w};
                    v2f sq = dy * dy + dx * dx;   // pk_fma(dy,dy, dx*dx)
                    acc[i][j] += (v2f){__builtin_amdgcn_sqrtf(sq.x),
                                       __builtin_amdgcn_sqrtf(sq.y)};
                }
            }
#pragma unroll
            for (int i = 0; i < 2; ++i) gv[i] = ngv[i];
            tv[0] = ntv[0];
            tv[1] = ntv[1];
        }
        // epilogue: s = NS-1
#pragma unroll
        for (int i = 0; i < 2; ++i) {
            v2f gx = {gv[i].x, gv[i].y};
            v2f gy = {gv[i].z, gv[i].w};
#pragma unroll
            for (int j = 0; j < 2; ++j) {
                v2f dx = gx - (v2f){tv[j].x, tv[j].y};
                v2f dy = gy - (v2f){tv[j].z, tv[j].w};
                v2f sq = dy * dy + dx * dx;
                acc[i][j] += (v2f){__builtin_amdgcn_sqrtf(sq.x),
                                   __builtin_amdgcn_sqrtf(sq.y)};
            }
        }

        const float inv_t = 1.0f / TT;
#pragma unroll
        for (int i = 0; i < 2; ++i) {
            pd[m][kb + 5 * i][tkp] = (acc[i][0].x + acc[i][0].y) * inv_t;
            if (tkp + 11 <= KK)                           // col 21 is dummy
                pd[m][kb + 5 * i][tkp + 11] = (acc[i][1].x + acc[i][1].y) * inv_t;
        }
    }
    __syncthreads();

    // ---- row/col mins over 20x20 + gt col: waves 0,1 (half==0), one per m ----
    if (half == 0) {
        float v = 0.f;
        float dg = FLT_MAX;
        if (lane < KK) {
            float rm = pd[m][lane][0];
#pragma unroll
            for (int j = 1; j < KK; ++j) rm = fminf(rm, pd[m][lane][j]);
            float cm = pd[m][0][lane];
#pragma unroll
            for (int j = 1; j < KK; ++j) cm = fminf(cm, pd[m][j][lane]);
            v = rm + cm;
            dg = pd[m][lane][KK];   // gt column
        }
#pragma unroll
        for (int off = 16; off > 0; off >>= 1) {
            v += __shfl_xor(v, off, 32);
            dg = fminf(dg, __shfl_xor(dg, off, 32));
        }

        if (lane == 0) {
            const size_t o = ((size_t)b * MM + (m0 + m)) * AA + a;
            ws_cham[o] = v * (1.0f / KK);
            ws_gt[o]   = dg;
        }
    }
}

// Single block: mean over A, min over M, mean over B, write 3 outputs.
// Dispatch boundary provides cross-XCD visibility of ws.
__global__ __launch_bounds__(512) void imle_final_kernel(
    const float* __restrict__ ws_cham,
    const float* __restrict__ ws_gt,
    float* __restrict__ out)
{
    __shared__ float ch[BB * MM], gv[BB * MM];
    __shared__ float mch[BB], mgt[BB];
    const int tid = threadIdx.x;  // 512 == B*M
    const int b = tid / MM, m = tid % MM;

    float sc = 0.f, sg = 0.f;
#pragma unroll
    for (int a = 0; a < AA; ++a) {
        sc += ws_cham[((size_t)b * MM + m) * AA + a];
        sg += ws_gt[((size_t)b * MM + m) * AA + a];
    }
    ch[tid] = sc * (1.0f / AA);
    gv[tid] = sg * (1.0f / AA);
    __syncthreads();

    if (tid < BB) {
        float c = ch[tid * MM], g = gv[tid * MM];
        for (int j = 1; j < MM; ++j) {
            c = fminf(c, ch[tid * MM + j]);
            g = fminf(g, gv[tid * MM + j]);
        }
        mch[tid] = c;
        mgt[tid] = g;
    }
    __syncthreads();

    if (tid == 0) {
        float lc = 0.f, lg = 0.f;
        for (int j = 0; j < BB; ++j) { lc += mch[j]; lg += mgt[j]; }
        lc *= (1.0f / BB);
        lg *= (1.0f / BB);
        out[0] = lc + lg;
        out[1] = lc;
        out[2] = lg;
    }
}

extern "C" void kernel_launch(void* const* d_in, const int* in_sizes, int n_in,
                              void* d_out, int out_size, void* d_ws, size_t ws_size,
                              hipStream_t stream) {
    const float* gen = (const float*)d_in[0];
    const float* tgt = (const float*)d_in[1];
    const float* gt  = (const float*)d_in[2];
    float* ws_cham = (float*)d_ws;                 // B*M*A floats
    float* ws_gt   = ws_cham + BB * MM * AA;       // B*M*A floats
    float* out     = (float*)d_out;

    imle_part_kernel<<<BB * AA * (MM / 2), 256, 0, stream>>>(gen, tgt, gt, ws_cham, ws_gt);
    imle_final_kernel<<<1, 512, 0, stream>>>(ws_cham, ws_gt, out);
}

// Round 7
// 81.368 us; speedup vs baseline: 1.0156x; 1.0156x over previous
//
#include <hip/hip_runtime.h>
#include <float.h>

#define BB 16
#define MM 32
#define KK 20
#define AA 8
#define TT 30
#define TD 60          // T*D floats per trajectory
#define NS 15          // float4 steps per trajectory (2 t-steps each)
#define KT 22          // target rows: 20 real + gt (row 20) + dummy (row 21)
#define PDS 21         // pd row stride in floats
#define NROW (40 + KT)           // 62 staged rows
#define NF4  (NROW * NS)         // 930 staged float4

typedef float v2f __attribute__((ext_vector_type(2)));

// One block = 2 waves = 2 m's sharing the target tile, for a fixed (b, a).
// grid = B*A*(M/2) = 2048 -> 8 blocks/CU (LDS 18.25 KB) -> 16 waves/CU.
// Two-dispatch structure: the single-dispatch last-block election line was
// abandoned (R1-R6: one +54us fence regression, one 20us MALL-atomic
// serialization, two container failures; best case saved ~5us).
//
// Staging is issue-all-loads-then-write: the harness's 256MB poison fill
// evicts the MALL every iteration, so staging reads are HBM-latency-bound
// (~900cy). Batching 8 independent global_load_dwordx4 per thread before
// the first ds_write collapses ~4 serialized round-trips into ~1.
__global__ __launch_bounds__(128, 4) void imle_part_kernel(
    const float* __restrict__ gen,   // B M K A T D
    const float* __restrict__ tgt,   // B K A T D
    const float* __restrict__ gt,    // B A T D
    float* __restrict__ ws_cham,     // [B][M][A]
    float* __restrict__ ws_gt)       // [B][M][A]
{
    __shared__ float4 sg[2][KK][NS];   // 2 m-slices of gen, x50, swizzled
    __shared__ float4 st[KT][NS];      // target rows (x50) + gt row + dummy
    __shared__ float  pd[2][KK][PDS];  // per-m pairwise mean distances

    const int blk = blockIdx.x;        // grid = 2048
    const int mg = blk & 15;           // m-group (M/2 = 16)
    const int a  = (blk >> 4) & 7;
    const int b  = blk >> 7;
    const int m0 = mg * 2;
    const int tid = threadIdx.x;

    // ---- staging pass 1: issue all global loads (independent, in flight) ----
    float4 vbuf[8];
#pragma unroll
    for (int u = 0; u < 8; ++u) {
        int idx = tid + u * 128;
        if (idx < NF4) {
            int row = idx / NS, q = idx - row * NS;
            const float4* src;
            if (row < 40) {                       // gen rows
                int mi = row / KK, k = row - mi * KK;
                src = (const float4*)(gen +
                    (size_t)(((b * MM + m0 + mi) * KK + k) * AA + a) * TD) + q;
            } else {
                int r = row - 40;                 // target rows
                if (r < KK)
                    src = (const float4*)(tgt + (size_t)((b * KK + r) * AA + a) * TD) + q;
                else                               // gt row (r==KK) and dummy (r==KK+1)
                    src = (const float4*)(gt + (size_t)(b * AA + a) * TD) + q;
            }
            vbuf[u] = *src;
        }
    }

    // ---- staging pass 2: swizzle (x1,y1,x2,y2)->(x1,x2,y1,y2), write LDS ----
#pragma unroll
    for (int u = 0; u < 8; ++u) {
        int idx = tid + u * 128;
        if (idx < NF4) {
            int row = idx / NS, q = idx - row * NS;
            float4 v = vbuf[u];
            if (row < 40) {
                int mi = row / KK, k = row - mi * KK;
                sg[mi][k][q] = make_float4(v.x * 50.f, v.z * 50.f, v.y * 50.f, v.w * 50.f);
            } else {
                int r = row - 40;
                float4 o;
                if (r < KK)      o = make_float4(v.x * 50.f, v.z * 50.f, v.y * 50.f, v.w * 50.f);
                else if (r == KK) o = make_float4(v.x, v.z, v.y, v.w);   // gt: metric scale
                else              o = make_float4(0.f, 0.f, 0.f, 0.f);   // dummy row
                st[r][q] = o;
            }
        }
    }
    __syncthreads();

    const int w = tid >> 6;        // wave id -> m offset (0 or 1)
    const int lane = tid & 63;

    // ---- pairwise distances: 4x2 register tile, software-pipelined s-loop ----
    if (lane < 55) {
        const int tk  = lane / 11;       // k  = tk + 5i
        const int tkp = lane - tk * 11;  // kp = tkp + 11j
        v2f acc[4][2] = {{{0.f,0.f},{0.f,0.f}},{{0.f,0.f},{0.f,0.f}},
                         {{0.f,0.f},{0.f,0.f}},{{0.f,0.f},{0.f,0.f}}};

        float4 gv[4], tv[2];
#pragma unroll
        for (int i = 0; i < 4; ++i) gv[i] = sg[w][tk + 5 * i][0];
        tv[0] = st[tkp][0];
        tv[1] = st[tkp + 11][0];

#pragma unroll 2
        for (int s = 0; s < NS - 1; ++s) {
            // prefetch s+1 (independent of current compute)
            float4 ngv[4], ntv[2];
#pragma unroll
            for (int i = 0; i < 4; ++i) ngv[i] = sg[w][tk + 5 * i][s + 1];
            ntv[0] = st[tkp][s + 1];
            ntv[1] = st[tkp + 11][s + 1];
            // compute on current: packed over the 2 t-steps in each float4
#pragma unroll
            for (int i = 0; i < 4; ++i) {
                v2f gx = {gv[i].x, gv[i].y};   // (x_t, x_{t+1})
                v2f gy = {gv[i].z, gv[i].w};   // (y_t, y_{t+1})
#pragma unroll
                for (int j = 0; j < 2; ++j) {
                    v2f dx = gx - (v2f){tv[j].x, tv[j].y};
                    v2f dy = gy - (v2f){tv[j].z, tv[j].w};
                    v2f sq = dy * dy + dx * dx;   // pk_fma(dy,dy, dx*dx)
                    acc[i][j] += (v2f){__builtin_amdgcn_sqrtf(sq.x),
                                       __builtin_amdgcn_sqrtf(sq.y)};
                }
            }
#pragma unroll
            for (int i = 0; i < 4; ++i) gv[i] = ngv[i];
            tv[0] = ntv[0];
            tv[1] = ntv[1];
        }
        // epilogue: s = NS-1
#pragma unroll
        for (int i = 0; i < 4; ++i) {
            v2f gx = {gv[i].x, gv[i].y};
            v2f gy = {gv[i].z, gv[i].w};
#pragma unroll
            for (int j = 0; j < 2; ++j) {
                v2f dx = gx - (v2f){tv[j].x, tv[j].y};
                v2f dy = gy - (v2f){tv[j].z, tv[j].w};
                v2f sq = dy * dy + dx * dx;
                acc[i][j] += (v2f){__builtin_amdgcn_sqrtf(sq.x),
                                   __builtin_amdgcn_sqrtf(sq.y)};
            }
        }

        const float inv_t = 1.0f / TT;
#pragma unroll
        for (int i = 0; i < 4; ++i) {
            pd[w][tk + 5 * i][tkp] = (acc[i][0].x + acc[i][0].y) * inv_t;
            if (tkp + 11 <= KK)                           // col 21 is dummy
                pd[w][tk + 5 * i][tkp + 11] = (acc[i][1].x + acc[i][1].y) * inv_t;
        }
    }
    __syncthreads();

    // ---- row/col mins over 20x20 + gt col, per wave / per m ----
    float v = 0.f;
    float dg = FLT_MAX;
    if (lane < KK) {
        float rm = pd[w][lane][0];
#pragma unroll
        for (int j = 1; j < KK; ++j) rm = fminf(rm, pd[w][lane][j]);
        float cm = pd[w][0][lane];
#pragma unroll
        for (int j = 1; j < KK; ++j) cm = fminf(cm, pd[w][j][lane]);
        v = rm + cm;
        dg = pd[w][lane][KK];   // gt column
    }
#pragma unroll
    for (int off = 16; off > 0; off >>= 1) {
        v += __shfl_xor(v, off, 32);
        dg = fminf(dg, __shfl_xor(dg, off, 32));
    }

    if (lane == 0) {
        const size_t o = ((size_t)b * MM + (m0 + w)) * AA + a;
        ws_cham[o] = v * (1.0f / KK);
        ws_gt[o]   = dg;
    }
}

// Single block: mean over A, min over M, mean over B, write 3 outputs.
// Dispatch boundary provides cross-XCD visibility of ws.
__global__ __launch_bounds__(512) void imle_final_kernel(
    const float* __restrict__ ws_cham,
    const float* __restrict__ ws_gt,
    float* __restrict__ out)
{
    __shared__ float ch[BB * MM], gv[BB * MM];
    __shared__ float mch[BB], mgt[BB];
    const int tid = threadIdx.x;  // 512 == B*M
    const int b = tid / MM, m = tid % MM;

    float sc = 0.f, sg = 0.f;
#pragma unroll
    for (int a = 0; a < AA; ++a) {
        sc += ws_cham[((size_t)b * MM + m) * AA + a];
        sg += ws_gt[((size_t)b * MM + m) * AA + a];
    }
    ch[tid] = sc * (1.0f / AA);
    gv[tid] = sg * (1.0f / AA);
    __syncthreads();

    if (tid < BB) {
        float c = ch[tid * MM], g = gv[tid * MM];
        for (int j = 1; j < MM; ++j) {
            c = fminf(c, ch[tid * MM + j]);
            g = fminf(g, gv[tid * MM + j]);
        }
        mch[tid] = c;
        mgt[tid] = g;
    }
    __syncthreads();

    if (tid == 0) {
        float lc = 0.f, lg = 0.f;
        for (int j = 0; j < BB; ++j) { lc += mch[j]; lg += mgt[j]; }
        lc *= (1.0f / BB);
        lg *= (1.0f / BB);
        out[0] = lc + lg;
        out[1] = lc;
        out[2] = lg;
    }
}

extern "C" void kernel_launch(void* const* d_in, const int* in_sizes, int n_in,
                              void* d_out, int out_size, void* d_ws, size_t ws_size,
                              hipStream_t stream) {
    const float* gen = (const float*)d_in[0];
    const float* tgt = (const float*)d_in[1];
    const float* gt  = (const float*)d_in[2];
    float* ws_cham = (float*)d_ws;                 // B*M*A floats
    float* ws_gt   = ws_cham + BB * MM * AA;       // B*M*A floats
    float* out     = (float*)d_out;

    imle_part_kernel<<<BB * AA * (MM / 2), 128, 0, stream>>>(gen, tgt, gt, ws_cham, ws_gt);
    imle_final_kernel<<<1, 512, 0, stream>>>(ws_cham, ws_gt, out);
}